// Round 6
// baseline (336.873 us; speedup 1.0000x reference)
//
#include <hip/hip_runtime.h>
#include <hip/hip_bf16.h>

#define B_EV    8192
#define R_NEG   32
#define DIM     256
#define K_COM   5
#define M_ROWS  (B_EV * (R_NEG + 2))   // 278528
#define BM      64
#define NT      (M_ROWS / BM)          // 4352 row-tiles
#define NBLK    512                    // persistent grid: 2 blocks/CU x 256 CU
#define N_NODES_C 100000

typedef _Float16 f16x8 __attribute__((ext_vector_type(8)));
typedef float    f32x4 __attribute__((ext_vector_type(4)));

#define MF(a, b, c) __builtin_amdgcn_mfma_f32_16x16x32_f16((a), (b), (c), 0, 0, 0)

// Load one B-fragment into a NAMED register variable (rule #20: no runtime-
// indexed arrays — named vars cannot be demoted to scratch).
// BV = B[k = KS_*32 + g*8 + j][col = w*64 + NT_*16 + l15], j=0..7
#define LDB(BV, NT_, KS_) do {                                   \
    const float* p_ = wbase + (size_t)((KS_) * 32) * DIM + (NT_) * 16; \
    BV[0] = (_Float16)p_[0 * DIM]; BV[1] = (_Float16)p_[1 * DIM]; \
    BV[2] = (_Float16)p_[2 * DIM]; BV[3] = (_Float16)p_[3 * DIM]; \
    BV[4] = (_Float16)p_[4 * DIM]; BV[5] = (_Float16)p_[5 * DIM]; \
    BV[6] = (_Float16)p_[6 * DIM]; BV[7] = (_Float16)p_[7 * DIM]; \
} while (0)

// One K-step (K=32): 4 A-fragment LDS reads + 16 MFMA, all-static indices.
#define KSTEP(KS_, B0_, B1_, B2_, B3_) do {                       \
    f16x8 av0 = xt8[((0 * 16 + l15) * 32 + (KS_) * 4 + g) ^ (l15 & 7)];        \
    f16x8 av1 = xt8[((1 * 16 + l15) * 32 + (KS_) * 4 + g) ^ ((16 + l15) & 7)]; \
    f16x8 av2 = xt8[((2 * 16 + l15) * 32 + (KS_) * 4 + g) ^ ((32 + l15) & 7)]; \
    f16x8 av3 = xt8[((3 * 16 + l15) * 32 + (KS_) * 4 + g) ^ ((48 + l15) & 7)]; \
    acc[0][0] = MF(av0, B0_, acc[0][0]); acc[1][0] = MF(av1, B0_, acc[1][0]);  \
    acc[2][0] = MF(av2, B0_, acc[2][0]); acc[3][0] = MF(av3, B0_, acc[3][0]);  \
    acc[0][1] = MF(av0, B1_, acc[0][1]); acc[1][1] = MF(av1, B1_, acc[1][1]);  \
    acc[2][1] = MF(av2, B1_, acc[2][1]); acc[3][1] = MF(av3, B1_, acc[3][1]);  \
    acc[0][2] = MF(av0, B2_, acc[0][2]); acc[1][2] = MF(av1, B2_, acc[1][2]);  \
    acc[2][2] = MF(av2, B2_, acc[2][2]); acc[3][2] = MF(av3, B2_, acc[3][2]);  \
    acc[0][3] = MF(av0, B3_, acc[0][3]); acc[1][3] = MF(av1, B3_, acc[1][3]);  \
    acc[2][3] = MF(av2, B3_, acc[2][3]); acc[3][3] = MF(av3, B3_, acc[3][3]);  \
} while (0)

// Persistent-block fused kernel. W1 B-fragments live in 32 NAMED f16x8
// registers (128 VGPR), loaded once per block, zero W1 traffic per tile.
// Fragment layouts proven by round-3 pass:
//   A-frag: lane holds A[row=l15][k=8g+j]; B-frag: B[k=8g+j][col=l15];
//   C/D:    lane holds D[row=4g+reg][col=l15].
__global__ __launch_bounds__(256, 2) void fused_kernel(
    const int* __restrict__ src, const int* __restrict__ dst,
    const int* __restrict__ neg, const float* __restrict__ ts,
    const float* __restrict__ state, const float* __restrict__ last_t,
    const float* __restrict__ log_decay,
    const float* __restrict__ W1, const float* __restrict__ b1,
    const float* __restrict__ W2, const float* __restrict__ b2,
    float* __restrict__ out)
{
    __shared__ f16x8 xt8[2048];            // 32 KB X tile [row][chunk^(row&7)]
    __shared__ int   node_s[64];
    __shared__ float gate_s[64];
    __shared__ float part[4][64][K_COM];   // 5 KB cross-wave partials

    const int tid  = threadIdx.x;
    const int lane = tid & 63;
    const int w    = tid >> 6;      // wave 0..3, owns h-cols w*64..w*64+63
    const int l15  = lane & 15;
    const int g    = lane >> 4;

    float ld    = log_decay[0];
    float decay = (ld > 30.f) ? ld : log1pf(expf(ld));   // stable softplus

    // ---- one-time: 32 named B-fragment registers ----
    const float* wbase = W1 + (size_t)(g * 8) * DIM + w * 64 + l15;
    f16x8 b00, b01, b02, b03, b04, b05, b06, b07;
    f16x8 b10, b11, b12, b13, b14, b15, b16, b17;
    f16x8 b20, b21, b22, b23, b24, b25, b26, b27;
    f16x8 b30, b31, b32, b33, b34, b35, b36, b37;
    LDB(b00, 0, 0); LDB(b01, 0, 1); LDB(b02, 0, 2); LDB(b03, 0, 3);
    LDB(b04, 0, 4); LDB(b05, 0, 5); LDB(b06, 0, 6); LDB(b07, 0, 7);
    LDB(b10, 1, 0); LDB(b11, 1, 1); LDB(b12, 1, 2); LDB(b13, 1, 3);
    LDB(b14, 1, 4); LDB(b15, 1, 5); LDB(b16, 1, 6); LDB(b17, 1, 7);
    LDB(b20, 2, 0); LDB(b21, 2, 1); LDB(b22, 2, 2); LDB(b23, 2, 3);
    LDB(b24, 2, 4); LDB(b25, 2, 5); LDB(b26, 2, 6); LDB(b27, 2, 7);
    LDB(b30, 3, 0); LDB(b31, 3, 1); LDB(b32, 3, 2); LDB(b33, 3, 3);
    LDB(b34, 3, 4); LDB(b35, 3, 5); LDB(b36, 3, 6); LDB(b37, 3, 7);

    // ---- persistent loop over row-tiles ----
    for (int t = blockIdx.x; t < NT; t += NBLK) {
        const int m0 = t * BM;

        if (tid < 64) {
            int m  = m0 + tid;
            int be = m / 34;
            int sl = m - be * 34;
            int node = (sl == 0) ? src[be] : (sl == 1) ? dst[be] : neg[be * R_NEG + (sl - 2)];
            if ((unsigned)node >= (unsigned)N_NODES_C) node = 0;
            float dtv = fmaxf(ts[be] - last_t[node], 0.f);
            node_s[tid] = node;
            gate_s[tid] = expf(-decay * dtv);
        }
        __syncthreads();   // barrier 1: node/gate visible

        // Stage X tile: 64 rows x 256 cols f16, gate applied, XOR-swizzled.
        {
            int c8 = tid & 31;
            int rb = tid >> 5;
            #pragma unroll
            for (int it = 0; it < 8; ++it) {
                int r = it * 8 + rb;
                int node = node_s[r];
                float gg = gate_s[r];
                const float* sp = state + (size_t)node * DIM + c8 * 8;
                float4 v0 = *(const float4*)(sp);
                float4 v1 = *(const float4*)(sp + 4);
                f16x8 pk;
                pk[0] = (_Float16)(v0.x * gg); pk[1] = (_Float16)(v0.y * gg);
                pk[2] = (_Float16)(v0.z * gg); pk[3] = (_Float16)(v0.w * gg);
                pk[4] = (_Float16)(v1.x * gg); pk[5] = (_Float16)(v1.y * gg);
                pk[6] = (_Float16)(v1.z * gg); pk[7] = (_Float16)(v1.w * gg);
                xt8[(r * 32 + c8) ^ (r & 7)] = pk;
            }
        }
        __syncthreads();   // barrier 2: X tile visible

        f32x4 acc[4][4];
        #pragma unroll
        for (int a = 0; a < 4; ++a)
            #pragma unroll
            for (int bb = 0; bb < 4; ++bb)
                acc[a][bb] = (f32x4){0.f, 0.f, 0.f, 0.f};

        KSTEP(0, b00, b10, b20, b30);
        KSTEP(1, b01, b11, b21, b31);
        KSTEP(2, b02, b12, b22, b32);
        KSTEP(3, b03, b13, b23, b33);
        KSTEP(4, b04, b14, b24, b34);
        KSTEP(5, b05, b15, b25, b35);
        KSTEP(6, b06, b16, b26, b36);
        KSTEP(7, b07, b17, b27, b37);

        // Epilogue: relu(h+b1)@W2, 16-lane shfl reduce, cross-wave partials.
        float b1v[4];
        float w2v[4][K_COM];
        #pragma unroll
        for (int nt = 0; nt < 4; ++nt) {
            int col = w * 64 + nt * 16 + l15;
            b1v[nt] = b1[col];
            #pragma unroll
            for (int k = 0; k < K_COM; ++k) w2v[nt][k] = W2[col * K_COM + k];
        }

        #pragma unroll
        for (int mt = 0; mt < 4; ++mt) {
            #pragma unroll
            for (int reg = 0; reg < 4; ++reg) {
                float p[K_COM] = {0.f, 0.f, 0.f, 0.f, 0.f};
                #pragma unroll
                for (int nt = 0; nt < 4; ++nt) {
                    float h = fmaxf(acc[mt][nt][reg] + b1v[nt], 0.f);
                    #pragma unroll
                    for (int k = 0; k < K_COM; ++k) p[k] += h * w2v[nt][k];
                }
                #pragma unroll
                for (int off = 8; off >= 1; off >>= 1)
                    #pragma unroll
                    for (int k = 0; k < K_COM; ++k) p[k] += __shfl_xor(p[k], off);
                if (l15 == 0) {
                    int row = mt * 16 + g * 4 + reg;
                    #pragma unroll
                    for (int k = 0; k < K_COM; ++k) part[w][row][k] = p[k];
                }
            }
        }
        __syncthreads();   // barrier 3: partials visible

        if (tid < 64) {
            float lg[K_COM];
            #pragma unroll
            for (int k = 0; k < K_COM; ++k)
                lg[k] = part[0][tid][k] + part[1][tid][k] + part[2][tid][k] + part[3][tid][k] + b2[k];
            float mx = lg[0];
            #pragma unroll
            for (int k = 1; k < K_COM; ++k) mx = fmaxf(mx, lg[k]);
            float sum = 0.f;
            #pragma unroll
            for (int k = 0; k < K_COM; ++k) { lg[k] = expf(lg[k] - mx); sum += lg[k]; }
            float inv = 1.f / sum;

            int m  = m0 + tid;
            int be = m / 34;
            int sl = m - be * 34;
            float* op;
            if (sl == 0)      op = out + (size_t)be * K_COM;
            else if (sl == 1) op = out + (size_t)B_EV * K_COM + (size_t)be * K_COM;
            else              op = out + (size_t)2 * B_EV * K_COM + ((size_t)be * R_NEG + (sl - 2)) * K_COM;
            #pragma unroll
            for (int k = 0; k < K_COM; ++k) op[k] = lg[k] * inv;
        }
        // next iteration's barrier 1 protects part[] / xt8 reuse
    }
}

extern "C" void kernel_launch(void* const* d_in, const int* in_sizes, int n_in,
                              void* d_out, int out_size, void* d_ws, size_t ws_size,
                              hipStream_t stream) {
    const int*   src       = (const int*)d_in[0];
    const int*   dst       = (const int*)d_in[1];
    const int*   neg       = (const int*)d_in[2];
    const float* ts        = (const float*)d_in[3];
    // d_in[4] = edge_idxs (unused by the reference)
    const float* state     = (const float*)d_in[5];
    const float* last_t    = (const float*)d_in[6];
    const float* log_decay = (const float*)d_in[7];
    const float* W1        = (const float*)d_in[8];
    const float* b1        = (const float*)d_in[9];
    const float* W2        = (const float*)d_in[10];
    const float* b2        = (const float*)d_in[11];

    fused_kernel<<<dim3(NBLK), dim3(256), 0, stream>>>(
        src, dst, neg, ts, state, last_t, log_decay, W1, b1, W2, b2,
        (float*)d_out);
}

// Round 7
// 282.631 us; speedup vs baseline: 1.1919x; 1.1919x over previous
//
#include <hip/hip_runtime.h>
#include <hip/hip_bf16.h>

#define B_EV    8192
#define R_NEG   32
#define DIM     256
#define K_COM   5
#define M_ROWS  (B_EV * (R_NEG + 2))   // 278528
#define NNODE   100000
#define Y_BYTES ((size_t)NNODE * DIM * 2)   // 51.2 MB f16
#define S1_BLK  ((NNODE + 63) / 64)    // 1563
#define S2_BLK  2048
#define NBLK    512                    // fallback persistent grid
#define NT_FB   (M_ROWS / 64)

typedef _Float16 f16x8 __attribute__((ext_vector_type(8)));
typedef float    f32x4 __attribute__((ext_vector_type(4)));

#define MF(a, b, c) __builtin_amdgcn_mfma_f32_16x16x32_f16((a), (b), (c), 0, 0, 0)

// ============================ STAGE 1 =====================================
// Y[node][col] (f16) = state[node] @ W1.  Per block: 64 rows x 256 cols.
// 8 waves; wave w owns cols w*32..w*32+31 -> 16 B-fragment regs (64 VGPR).
// Proven layouts (round 3): A-frag lane=(g,l15): A[row=l15+16mt][k=8g+j];
// B-frag: B[k=8g+j][col=l15]; D: D[row=4g+reg][col=l15].
#define LDB2(BV, NT_, KS_) do {                                          \
    const float* p_ = wbase + (size_t)((KS_) * 32) * DIM + (NT_) * 16;   \
    BV[0] = (_Float16)p_[0 * DIM]; BV[1] = (_Float16)p_[1 * DIM];        \
    BV[2] = (_Float16)p_[2 * DIM]; BV[3] = (_Float16)p_[3 * DIM];        \
    BV[4] = (_Float16)p_[4 * DIM]; BV[5] = (_Float16)p_[5 * DIM];        \
    BV[6] = (_Float16)p_[6 * DIM]; BV[7] = (_Float16)p_[7 * DIM];        \
} while (0)

#define KSTEP2(KS_, B0_, B1_) do {                                       \
    f16x8 av0 = xt8[(( 0 + l15) * 32 + (KS_) * 4 + g) ^ (l15 & 7)];      \
    f16x8 av1 = xt8[((16 + l15) * 32 + (KS_) * 4 + g) ^ (l15 & 7)];      \
    f16x8 av2 = xt8[((32 + l15) * 32 + (KS_) * 4 + g) ^ (l15 & 7)];      \
    f16x8 av3 = xt8[((48 + l15) * 32 + (KS_) * 4 + g) ^ (l15 & 7)];      \
    acc[0][0] = MF(av0, B0_, acc[0][0]); acc[1][0] = MF(av1, B0_, acc[1][0]); \
    acc[2][0] = MF(av2, B0_, acc[2][0]); acc[3][0] = MF(av3, B0_, acc[3][0]); \
    acc[0][1] = MF(av0, B1_, acc[0][1]); acc[1][1] = MF(av1, B1_, acc[1][1]); \
    acc[2][1] = MF(av2, B1_, acc[2][1]); acc[3][1] = MF(av3, B1_, acc[3][1]); \
} while (0)

__global__ __launch_bounds__(512, 2) void s1_gemm(
    const float* __restrict__ state, const float* __restrict__ W1,
    _Float16* __restrict__ Y)
{
    __shared__ f16x8 xt8[2048];   // 32 KB A tile [row][c8 ^ (row&7)]
    __shared__ f16x8 ot8[2048];   // 32 KB out tile, same swizzle

    const int tid  = threadIdx.x;
    const int lane = tid & 63;
    const int w    = tid >> 6;     // wave 0..7, cols w*32..
    const int l15  = lane & 15;
    const int g    = lane >> 4;
    const int m0   = blockIdx.x * 64;

    // B-fragments: 16 named regs (64 VGPR), loaded once.
    const float* wbase = W1 + (size_t)(g * 8) * DIM + w * 32 + l15;
    f16x8 b00, b01, b02, b03, b04, b05, b06, b07;
    f16x8 b10, b11, b12, b13, b14, b15, b16, b17;
    LDB2(b00, 0, 0); LDB2(b01, 0, 1); LDB2(b02, 0, 2); LDB2(b03, 0, 3);
    LDB2(b04, 0, 4); LDB2(b05, 0, 5); LDB2(b06, 0, 6); LDB2(b07, 0, 7);
    LDB2(b10, 1, 0); LDB2(b11, 1, 1); LDB2(b12, 1, 2); LDB2(b13, 1, 3);
    LDB2(b14, 1, 4); LDB2(b15, 1, 5); LDB2(b16, 1, 6); LDB2(b17, 1, 7);

    // Stage A tile: rows m0..m0+63 (clamped), f16, swizzled.
    #pragma unroll
    for (int s = 0; s < 4; ++s) {
        int cid = tid + s * 512;          // 0..2047
        int row = cid >> 5, c8 = cid & 31;
        int m = m0 + row; if (m > NNODE - 1) m = NNODE - 1;
        const float* sp = state + (size_t)m * DIM + c8 * 8;
        float4 v0 = *(const float4*)(sp);
        float4 v1 = *(const float4*)(sp + 4);
        f16x8 pk;
        pk[0] = (_Float16)v0.x; pk[1] = (_Float16)v0.y;
        pk[2] = (_Float16)v0.z; pk[3] = (_Float16)v0.w;
        pk[4] = (_Float16)v1.x; pk[5] = (_Float16)v1.y;
        pk[6] = (_Float16)v1.z; pk[7] = (_Float16)v1.w;
        xt8[row * 32 + (c8 ^ (row & 7))] = pk;
    }
    __syncthreads();

    f32x4 acc[4][2];
    #pragma unroll
    for (int a = 0; a < 4; ++a) { acc[a][0] = (f32x4){0,0,0,0}; acc[a][1] = (f32x4){0,0,0,0}; }

    KSTEP2(0, b00, b10); KSTEP2(1, b01, b11);
    KSTEP2(2, b02, b12); KSTEP2(3, b03, b13);
    KSTEP2(4, b04, b14); KSTEP2(5, b05, b15);
    KSTEP2(6, b06, b16); KSTEP2(7, b07, b17);

    // Write D to swizzled LDS (f16), then coalesced global store.
    _Float16* ot16 = (_Float16*)ot8;
    #pragma unroll
    for (int mt = 0; mt < 4; ++mt)
        #pragma unroll
        for (int nt = 0; nt < 2; ++nt) {
            int c8o = w * 4 + nt * 2 + (l15 >> 3);
            int j   = l15 & 7;
            #pragma unroll
            for (int reg = 0; reg < 4; ++reg) {
                int row = mt * 16 + g * 4 + reg;
                ot16[(row * 32 + (c8o ^ (row & 7))) * 8 + j] = (_Float16)acc[mt][nt][reg];
            }
        }
    __syncthreads();

    #pragma unroll
    for (int s = 0; s < 4; ++s) {
        int cid = tid + s * 512;
        int row = cid >> 5, c8 = cid & 31;
        int m = m0 + row;
        if (m < NNODE)
            *(f16x8*)(Y + (size_t)m * DIM + c8 * 8) = ot8[row * 32 + (c8 ^ (row & 7))];
    }
}

// ============================ STAGE 2 =====================================
// Per event-row: gather Y[node], h = relu(gate*y + b1), logits = h@W2 + b2,
// softmax, scatter. One row per 16-lane group (4 rows/wave).
__global__ void s2_head(
    const int* __restrict__ src, const int* __restrict__ dst,
    const int* __restrict__ neg, const float* __restrict__ ts,
    const float* __restrict__ last_t, const float* __restrict__ log_decay,
    const _Float16* __restrict__ Y, const float* __restrict__ b1,
    const float* __restrict__ W2, const float* __restrict__ b2,
    float* __restrict__ out)
{
    const int tid  = threadIdx.x;
    const int lane = tid & 63;
    const int grp  = lane >> 4;        // 0..3: row within wave-iteration
    const int l    = lane & 15;
    const int wid  = blockIdx.x * 4 + (tid >> 6);

    float ld    = log_decay[0];
    float decay = (ld > 30.f) ? ld : log1pf(expf(ld));

    // Preload this lane's 16 cols of W2/b1: cols l*8+jj and 128+l*8+jj.
    float b1a[8], b1b[8], w2a[8][K_COM], w2b[8][K_COM];
    #pragma unroll
    for (int jj = 0; jj < 8; ++jj) {
        int ca = l * 8 + jj, cb = 128 + l * 8 + jj;
        b1a[jj] = b1[ca]; b1b[jj] = b1[cb];
        #pragma unroll
        for (int k = 0; k < K_COM; ++k) {
            w2a[jj][k] = W2[ca * K_COM + k];
            w2b[jj][k] = W2[cb * K_COM + k];
        }
    }
    float bb[K_COM];
    #pragma unroll
    for (int k = 0; k < K_COM; ++k) bb[k] = b2[k];

    for (int r4 = wid * 4; r4 < M_ROWS; r4 += S2_BLK * 4 * 4) {
        int row = r4 + grp;
        int be  = row / 34;
        int sl  = row - be * 34;
        int node = (sl == 0) ? src[be] : (sl == 1) ? dst[be] : neg[be * R_NEG + (sl - 2)];
        if ((unsigned)node >= (unsigned)NNODE) node = 0;
        float dtv  = fmaxf(ts[be] - last_t[node], 0.f);
        float gate = expf(-decay * dtv);

        const f16x8* yp = (const f16x8*)(Y + (size_t)node * DIM);
        f16x8 y0 = yp[l];        // cols l*8 .. +7      (coalesced 16B/lane)
        f16x8 y1 = yp[16 + l];   // cols 128+l*8 .. +7

        float p[K_COM] = {0.f, 0.f, 0.f, 0.f, 0.f};
        #pragma unroll
        for (int jj = 0; jj < 8; ++jj) {
            float h = fmaxf(fmaf(gate, (float)y0[jj], b1a[jj]), 0.f);
            #pragma unroll
            for (int k = 0; k < K_COM; ++k) p[k] = fmaf(h, w2a[jj][k], p[k]);
            float h2 = fmaxf(fmaf(gate, (float)y1[jj], b1b[jj]), 0.f);
            #pragma unroll
            for (int k = 0; k < K_COM; ++k) p[k] = fmaf(h2, w2b[jj][k], p[k]);
        }
        #pragma unroll
        for (int off = 8; off >= 1; off >>= 1)
            #pragma unroll
            for (int k = 0; k < K_COM; ++k) p[k] += __shfl_xor(p[k], off);

        float lg[K_COM];
        #pragma unroll
        for (int k = 0; k < K_COM; ++k) lg[k] = p[k] + bb[k];
        float mx = lg[0];
        #pragma unroll
        for (int k = 1; k < K_COM; ++k) mx = fmaxf(mx, lg[k]);
        float sum = 0.f;
        #pragma unroll
        for (int k = 0; k < K_COM; ++k) { lg[k] = expf(lg[k] - mx); sum += lg[k]; }
        float inv = 1.f / sum;

        if (l == 0) {
            float* op;
            if (sl == 0)      op = out + (size_t)be * K_COM;
            else if (sl == 1) op = out + (size_t)B_EV * K_COM + (size_t)be * K_COM;
            else              op = out + (size_t)2 * B_EV * K_COM + ((size_t)be * R_NEG + (sl - 2)) * K_COM;
            #pragma unroll
            for (int k = 0; k < K_COM; ++k) op[k] = lg[k] * inv;
        }
    }
}

// ===================== FALLBACK (round-6 proven kernel) ====================
#define FLDB(BV, NT_, KS_) do {                                   \
    const float* p_ = wbase + (size_t)((KS_) * 32) * DIM + (NT_) * 16; \
    BV[0] = (_Float16)p_[0 * DIM]; BV[1] = (_Float16)p_[1 * DIM]; \
    BV[2] = (_Float16)p_[2 * DIM]; BV[3] = (_Float16)p_[3 * DIM]; \
    BV[4] = (_Float16)p_[4 * DIM]; BV[5] = (_Float16)p_[5 * DIM]; \
    BV[6] = (_Float16)p_[6 * DIM]; BV[7] = (_Float16)p_[7 * DIM]; \
} while (0)

#define FKSTEP(KS_, B0_, B1_, B2_, B3_) do {                      \
    f16x8 av0 = xt8[((0 * 16 + l15) * 32 + (KS_) * 4 + g) ^ (l15 & 7)]; \
    f16x8 av1 = xt8[((1 * 16 + l15) * 32 + (KS_) * 4 + g) ^ (l15 & 7)]; \
    f16x8 av2 = xt8[((2 * 16 + l15) * 32 + (KS_) * 4 + g) ^ (l15 & 7)]; \
    f16x8 av3 = xt8[((3 * 16 + l15) * 32 + (KS_) * 4 + g) ^ (l15 & 7)]; \
    acc[0][0] = MF(av0, B0_, acc[0][0]); acc[1][0] = MF(av1, B0_, acc[1][0]);  \
    acc[2][0] = MF(av2, B0_, acc[2][0]); acc[3][0] = MF(av3, B0_, acc[3][0]);  \
    acc[0][1] = MF(av0, B1_, acc[0][1]); acc[1][1] = MF(av1, B1_, acc[1][1]);  \
    acc[2][1] = MF(av2, B1_, acc[2][1]); acc[3][1] = MF(av3, B1_, acc[3][1]);  \
    acc[0][2] = MF(av0, B2_, acc[0][2]); acc[1][2] = MF(av1, B2_, acc[1][2]);  \
    acc[2][2] = MF(av2, B2_, acc[2][2]); acc[3][2] = MF(av3, B2_, acc[3][2]);  \
    acc[0][3] = MF(av0, B3_, acc[0][3]); acc[1][3] = MF(av1, B3_, acc[1][3]);  \
    acc[2][3] = MF(av2, B3_, acc[2][3]); acc[3][3] = MF(av3, B3_, acc[3][3]);  \
} while (0)

__global__ __launch_bounds__(256, 2) void fused_fallback(
    const int* __restrict__ src, const int* __restrict__ dst,
    const int* __restrict__ neg, const float* __restrict__ ts,
    const float* __restrict__ state, const float* __restrict__ last_t,
    const float* __restrict__ log_decay,
    const float* __restrict__ W1, const float* __restrict__ b1,
    const float* __restrict__ W2, const float* __restrict__ b2,
    float* __restrict__ out)
{
    __shared__ f16x8 xt8[2048];
    __shared__ int   node_s[64];
    __shared__ float gate_s[64];
    __shared__ float part[4][64][K_COM];

    const int tid  = threadIdx.x;
    const int lane = tid & 63;
    const int w    = tid >> 6;
    const int l15  = lane & 15;
    const int g    = lane >> 4;

    float ld    = log_decay[0];
    float decay = (ld > 30.f) ? ld : log1pf(expf(ld));

    const float* wbase = W1 + (size_t)(g * 8) * DIM + w * 64 + l15;
    f16x8 b00, b01, b02, b03, b04, b05, b06, b07;
    f16x8 b10, b11, b12, b13, b14, b15, b16, b17;
    f16x8 b20, b21, b22, b23, b24, b25, b26, b27;
    f16x8 b30, b31, b32, b33, b34, b35, b36, b37;
    FLDB(b00, 0, 0); FLDB(b01, 0, 1); FLDB(b02, 0, 2); FLDB(b03, 0, 3);
    FLDB(b04, 0, 4); FLDB(b05, 0, 5); FLDB(b06, 0, 6); FLDB(b07, 0, 7);
    FLDB(b10, 1, 0); FLDB(b11, 1, 1); FLDB(b12, 1, 2); FLDB(b13, 1, 3);
    FLDB(b14, 1, 4); FLDB(b15, 1, 5); FLDB(b16, 1, 6); FLDB(b17, 1, 7);
    FLDB(b20, 2, 0); FLDB(b21, 2, 1); FLDB(b22, 2, 2); FLDB(b23, 2, 3);
    FLDB(b24, 2, 4); FLDB(b25, 2, 5); FLDB(b26, 2, 6); FLDB(b27, 2, 7);
    FLDB(b30, 3, 0); FLDB(b31, 3, 1); FLDB(b32, 3, 2); FLDB(b33, 3, 3);
    FLDB(b34, 3, 4); FLDB(b35, 3, 5); FLDB(b36, 3, 6); FLDB(b37, 3, 7);

    for (int t = blockIdx.x; t < NT_FB; t += NBLK) {
        const int m0 = t * 64;
        if (tid < 64) {
            int m  = m0 + tid;
            int be = m / 34;
            int sl = m - be * 34;
            int node = (sl == 0) ? src[be] : (sl == 1) ? dst[be] : neg[be * R_NEG + (sl - 2)];
            if ((unsigned)node >= (unsigned)NNODE) node = 0;
            float dtv = fmaxf(ts[be] - last_t[node], 0.f);
            node_s[tid] = node;
            gate_s[tid] = expf(-decay * dtv);
        }
        __syncthreads();
        {
            int c8 = tid & 31;
            int rb = tid >> 5;
            #pragma unroll
            for (int it = 0; it < 8; ++it) {
                int r = it * 8 + rb;
                int node = node_s[r];
                float gg = gate_s[r];
                const float* sp = state + (size_t)node * DIM + c8 * 8;
                float4 v0 = *(const float4*)(sp);
                float4 v1 = *(const float4*)(sp + 4);
                f16x8 pk;
                pk[0] = (_Float16)(v0.x * gg); pk[1] = (_Float16)(v0.y * gg);
                pk[2] = (_Float16)(v0.z * gg); pk[3] = (_Float16)(v0.w * gg);
                pk[4] = (_Float16)(v1.x * gg); pk[5] = (_Float16)(v1.y * gg);
                pk[6] = (_Float16)(v1.z * gg); pk[7] = (_Float16)(v1.w * gg);
                xt8[(r * 32 + c8) ^ (r & 7)] = pk;
            }
        }
        __syncthreads();

        f32x4 acc[4][4];
        #pragma unroll
        for (int a = 0; a < 4; ++a)
            #pragma unroll
            for (int bq = 0; bq < 4; ++bq) acc[a][bq] = (f32x4){0,0,0,0};

        FKSTEP(0, b00, b10, b20, b30); FKSTEP(1, b01, b11, b21, b31);
        FKSTEP(2, b02, b12, b22, b32); FKSTEP(3, b03, b13, b23, b33);
        FKSTEP(4, b04, b14, b24, b34); FKSTEP(5, b05, b15, b25, b35);
        FKSTEP(6, b06, b16, b26, b36); FKSTEP(7, b07, b17, b27, b37);

        float b1v[4];
        float w2v[4][K_COM];
        #pragma unroll
        for (int nt = 0; nt < 4; ++nt) {
            int col = w * 64 + nt * 16 + l15;
            b1v[nt] = b1[col];
            #pragma unroll
            for (int k = 0; k < K_COM; ++k) w2v[nt][k] = W2[col * K_COM + k];
        }
        #pragma unroll
        for (int mt = 0; mt < 4; ++mt)
            #pragma unroll
            for (int reg = 0; reg < 4; ++reg) {
                float p[K_COM] = {0.f, 0.f, 0.f, 0.f, 0.f};
                #pragma unroll
                for (int nt = 0; nt < 4; ++nt) {
                    float h = fmaxf(acc[mt][nt][reg] + b1v[nt], 0.f);
                    #pragma unroll
                    for (int k = 0; k < K_COM; ++k) p[k] += h * w2v[nt][k];
                }
                #pragma unroll
                for (int off = 8; off >= 1; off >>= 1)
                    #pragma unroll
                    for (int k = 0; k < K_COM; ++k) p[k] += __shfl_xor(p[k], off);
                if (l15 == 0) {
                    int row = mt * 16 + g * 4 + reg;
                    #pragma unroll
                    for (int k = 0; k < K_COM; ++k) part[w][row][k] = p[k];
                }
            }
        __syncthreads();

        if (tid < 64) {
            float lg[K_COM];
            #pragma unroll
            for (int k = 0; k < K_COM; ++k)
                lg[k] = part[0][tid][k] + part[1][tid][k] + part[2][tid][k] + part[3][tid][k] + b2[k];
            float mx = lg[0];
            #pragma unroll
            for (int k = 1; k < K_COM; ++k) mx = fmaxf(mx, lg[k]);
            float sum = 0.f;
            #pragma unroll
            for (int k = 0; k < K_COM; ++k) { lg[k] = expf(lg[k] - mx); sum += lg[k]; }
            float inv = 1.f / sum;
            int m  = m0 + tid;
            int be = m / 34;
            int sl = m - be * 34;
            float* op;
            if (sl == 0)      op = out + (size_t)be * K_COM;
            else if (sl == 1) op = out + (size_t)B_EV * K_COM + (size_t)be * K_COM;
            else              op = out + (size_t)2 * B_EV * K_COM + ((size_t)be * R_NEG + (sl - 2)) * K_COM;
            #pragma unroll
            for (int k = 0; k < K_COM; ++k) op[k] = lg[k] * inv;
        }
    }
}

extern "C" void kernel_launch(void* const* d_in, const int* in_sizes, int n_in,
                              void* d_out, int out_size, void* d_ws, size_t ws_size,
                              hipStream_t stream) {
    const int*   src       = (const int*)d_in[0];
    const int*   dst       = (const int*)d_in[1];
    const int*   neg       = (const int*)d_in[2];
    const float* ts        = (const float*)d_in[3];
    // d_in[4] = edge_idxs (unused by the reference)
    const float* state     = (const float*)d_in[5];
    const float* last_t    = (const float*)d_in[6];
    const float* log_decay = (const float*)d_in[7];
    const float* W1        = (const float*)d_in[8];
    const float* b1        = (const float*)d_in[9];
    const float* W2        = (const float*)d_in[10];
    const float* b2        = (const float*)d_in[11];

    if (ws_size >= Y_BYTES) {
        _Float16* Y = (_Float16*)d_ws;
        s1_gemm<<<dim3(S1_BLK), dim3(512), 0, stream>>>(state, W1, Y);
        s2_head<<<dim3(S2_BLK), dim3(256), 0, stream>>>(
            src, dst, neg, ts, last_t, log_decay, Y, b1, W2, b2, (float*)d_out);
    } else {
        fused_fallback<<<dim3(NBLK), dim3(256), 0, stream>>>(
            src, dst, neg, ts, state, last_t, log_decay, W1, b1, W2, b2,
            (float*)d_out);
    }
}